// Round 1
// baseline (732.238 us; speedup 1.0000x reference)
//
#include <hip/hip_runtime.h>
#include <math.h>

#define S_ 2048
#define R_ 384
#define C_ 64
// ws layout (floats): kv[R*S*16] | qpart[16*R*64] | o[R*64]  (~52 MB)

// LayerNorm of one 64-float row spread across a 16-lane group (lane holds 4
// consecutive c at c4). Wave-synchronous shfl reduction within the group.
__device__ __forceinline__ float4 ln_quad(const float4 x4, const float* lnw,
                                          const float* lnb, int c4) {
  float s1 = x4.x + x4.y + x4.z + x4.w;
  float s2 = fmaf(x4.x, x4.x, fmaf(x4.y, x4.y, fmaf(x4.z, x4.z, x4.w * x4.w)));
#pragma unroll
  for (int msk = 1; msk <= 8; msk <<= 1) {
    s1 += __shfl_xor(s1, msk);
    s2 += __shfl_xor(s2, msk);
  }
  float mu  = s1 * (1.f / 64.f);
  float var = fmaf(-mu, mu, s2 * (1.f / 64.f));
  float inv = rsqrtf(var + 1e-5f);
  float nb  = -mu * inv;
  float4 xl;
  xl.x = fmaf(fmaf(x4.x, inv, nb), lnw[c4 + 0], lnb[c4 + 0]);
  xl.y = fmaf(fmaf(x4.y, inv, nb), lnw[c4 + 1], lnb[c4 + 1]);
  xl.z = fmaf(fmaf(x4.z, inv, nb), lnw[c4 + 2], lnb[c4 + 2]);
  xl.w = fmaf(fmaf(x4.w, inv, nb), lnw[c4 + 3], lnb[c4 + 3]);
  return xl;
}

// ---------------- Kernel 1: LN + K/V + partial Q-sums ----------------
// grid (16, R), block 256 (4 waves). Block handles 128 s-rows of column r.
__global__ __launch_bounds__(256) void k_lnkv(
    const float* __restrict__ m, const float* __restrict__ lnw_g,
    const float* __restrict__ lnb_g, const float* __restrict__ Wk,
    const float* __restrict__ Wv, float* __restrict__ kv,
    float* __restrict__ qpart) {
  __shared__ float WT[16 * 72];        // transposed [j][c], pad 72 (bank-safe)
  __shared__ float lnw[64], lnb[64];
  __shared__ float xbuf[4][4 * 72];    // per-wave 4 rows, stride 72
  __shared__ float qred[4][64];

  const int t = threadIdx.x;
  const int w = t >> 6, l = t & 63;
  const int r = blockIdx.y, chunk = blockIdx.x;

  for (int idx = t; idx < 16 * 64; idx += 256) {
    int j = idx >> 6, c = idx & 63;
    WT[j * 72 + c] = (j < 8) ? Wk[c * 8 + j] : Wv[c * 8 + (j - 8)];
  }
  if (t < 64) { lnw[t] = lnw_g[t]; lnb[t] = lnb_g[t]; }
  __syncthreads();

  const int rs = l >> 4;          // row slot for load/LN
  const int c4 = (l & 15) * 4;    // c quad
  const int jj = l >> 2;          // gemm output 0..15 (k:0-7, v:8-15)
  const int rg = l & 3;           // gemm row slot
  const int sbase = chunk * 128 + w * 32;
  float* xb = xbuf[w];

  float4 qacc = make_float4(0.f, 0.f, 0.f, 0.f);

  for (int g = 0; g < 8; ++g) {
    const int s = sbase + g * 4 + rs;
    const float4 x4 = *(const float4*)(m + ((size_t)s * R_ + r) * C_ + c4);
    const float4 xl = ln_quad(x4, lnw, lnb, c4);
    qacc.x += xl.x; qacc.y += xl.y; qacc.z += xl.z; qacc.w += xl.w;
    *(float4*)(xb + rs * 72 + c4) = xl;
    __builtin_amdgcn_wave_barrier();
    // dot(xbuf[rg], WT[jj]) over c=0..63
    float4 acc = make_float4(0.f, 0.f, 0.f, 0.f);
#pragma unroll
    for (int c = 0; c < 64; c += 4) {
      const float4 xv = *(const float4*)(xb + rg * 72 + c);
      const float4 wv = *(const float4*)(WT + jj * 72 + c);
      acc.x = fmaf(xv.x, wv.x, acc.x);
      acc.y = fmaf(xv.y, wv.y, acc.y);
      acc.z = fmaf(xv.z, wv.z, acc.z);
      acc.w = fmaf(xv.w, wv.w, acc.w);
    }
    kv[((size_t)r * S_ + sbase + g * 4) * 16 + rg * 16 + jj] =
        (acc.x + acc.y) + (acc.z + acc.w);
    __builtin_amdgcn_wave_barrier();
  }
  // reduce q partials across the 4 row slots (lane bits 4,5)
#pragma unroll
  for (int msk = 16; msk <= 32; msk <<= 1) {
    qacc.x += __shfl_xor(qacc.x, msk);
    qacc.y += __shfl_xor(qacc.y, msk);
    qacc.z += __shfl_xor(qacc.z, msk);
    qacc.w += __shfl_xor(qacc.w, msk);
  }
  if (l < 16) *(float4*)(&qred[w][c4]) = qacc;
  __syncthreads();
  if (t < 64) {
    float q = qred[0][t] + qred[1][t] + qred[2][t] + qred[3][t];
    qpart[((size_t)chunk * R_ + r) * 64 + t] = q;
  }
}

// ---------------- Kernel 2: pooled q + attention ----------------
// grid (R), block 256. Two-pass softmax with logit recomputation.
// Thread map: h = t&7, part = t>>3 (32 parts x 64 s).
__global__ __launch_bounds__(256) void k_attn(
    const float* __restrict__ qpart, const float* __restrict__ Wq,
    const float* __restrict__ kv, float* __restrict__ o_ws) {
  __shared__ float qs[64];
  __shared__ float q[64];
  __shared__ float mred[8 * 32];
  __shared__ float lred[8 * 32];
  __shared__ float opart[32 * 64];

  const int t = threadIdx.x, r = blockIdx.x;

  if (t < 64) {
    float s = 0.f;
#pragma unroll
    for (int ch = 0; ch < 16; ++ch) s += qpart[((size_t)ch * R_ + r) * 64 + t];
    qs[t] = s * (1.f / 2048.f);   // /(S+1e-10) rounds to /2048 in fp32
  }
  __syncthreads();
  if (t < 64) {
    float acc = 0.f;
    for (int c = 0; c < 64; ++c) acc = fmaf(qs[c], Wq[c * 64 + t], acc);
    q[t] = acc * 0.35355339059327373f;   // Ch^-0.5
  }
  __syncthreads();

  const int h = t & 7, part = t >> 3;
  const float4 qh0 = *(const float4*)(&q[h * 8]);
  const float4 qh1 = *(const float4*)(&q[h * 8 + 4]);

  // pass 1: per-head max of logits over this thread's s range
  float mx = -1e30f;
  for (int s = part * 64; s < part * 64 + 64; ++s) {
    const float* kp = kv + ((size_t)r * S_ + s) * 16;
    const float4 k0 = *(const float4*)(kp);
    const float4 k1 = *(const float4*)(kp + 4);
    float d = fmaf(qh0.x, k0.x, fmaf(qh0.y, k0.y, fmaf(qh0.z, k0.z,
              fmaf(qh0.w, k0.w, fmaf(qh1.x, k1.x, fmaf(qh1.y, k1.y,
              fmaf(qh1.z, k1.z, qh1.w * k1.w)))))));
    mx = fmaxf(mx, d);
  }
  mred[h * 32 + part] = mx;
  __syncthreads();
  float mh = -1e30f;
  for (int p = 0; p < 32; ++p) mh = fmaxf(mh, mred[h * 32 + p]);

  // pass 2: exp-sum + unnormalized o accumulation
  float l_acc = 0.f;
  float4 av0 = make_float4(0.f, 0.f, 0.f, 0.f);
  float4 av1 = make_float4(0.f, 0.f, 0.f, 0.f);
  for (int s = part * 64; s < part * 64 + 64; ++s) {
    const float* kp = kv + ((size_t)r * S_ + s) * 16;
    const float4 k0 = *(const float4*)(kp);
    const float4 k1 = *(const float4*)(kp + 4);
    const float4 v0 = *(const float4*)(kp + 8);
    const float4 v1 = *(const float4*)(kp + 12);
    float d = fmaf(qh0.x, k0.x, fmaf(qh0.y, k0.y, fmaf(qh0.z, k0.z,
              fmaf(qh0.w, k0.w, fmaf(qh1.x, k1.x, fmaf(qh1.y, k1.y,
              fmaf(qh1.z, k1.z, qh1.w * k1.w)))))));
    float e = __expf(d - mh);
    l_acc += e;
    av0.x = fmaf(e, v0.x, av0.x); av0.y = fmaf(e, v0.y, av0.y);
    av0.z = fmaf(e, v0.z, av0.z); av0.w = fmaf(e, v0.w, av0.w);
    av1.x = fmaf(e, v1.x, av1.x); av1.y = fmaf(e, v1.y, av1.y);
    av1.z = fmaf(e, v1.z, av1.z); av1.w = fmaf(e, v1.w, av1.w);
  }
  lred[h * 32 + part] = l_acc;
  *(float4*)(&opart[part * 64 + h * 8])     = av0;
  *(float4*)(&opart[part * 64 + h * 8 + 4]) = av1;
  __syncthreads();

  if (t < 64) {
    const int hh = t >> 3;
    float denom = 0.f;
    for (int p = 0; p < 32; ++p) denom += lred[hh * 32 + p];
    float acc = 0.f;
    for (int p = 0; p < 32; ++p) acc += opart[p * 64 + t];
    o_ws[(size_t)r * 64 + t] = acc / denom;
  }
}

// ---------------- Kernel 3: gate + output projection ----------------
// grid (32, R), block 256 (4 waves). Block handles 64 s-rows of column r.
__global__ __launch_bounds__(256) void k_out(
    const float* __restrict__ m, const float* __restrict__ lnw_g,
    const float* __restrict__ lnb_g, const float* __restrict__ Wg,
    const float* __restrict__ bg, const float* __restrict__ Wo,
    const float* __restrict__ bo, const float* __restrict__ o_ws,
    float* __restrict__ out) {
  __shared__ float Wg_s[64 * 64];
  __shared__ float Wo_s[64 * 64];
  __shared__ float lnw[64], lnb[64], bg_s[64], bo_s[64], o_s[64];
  __shared__ float xbuf[4][4 * 72];

  const int t = threadIdx.x;
  const int w = t >> 6, l = t & 63;
  const int r = blockIdx.y, chunk = blockIdx.x;

  for (int idx = t; idx < 64 * 64; idx += 256) {
    Wg_s[idx] = Wg[idx];
    Wo_s[idx] = Wo[idx];
  }
  if (t < 64) {
    lnw[t] = lnw_g[t]; lnb[t] = lnb_g[t];
    bg_s[t] = bg[t];   bo_s[t] = bo[t];
    o_s[t] = o_ws[(size_t)r * 64 + t];
  }
  __syncthreads();

  const int rs = l >> 4;
  const int c4 = (l & 15) * 4;
  const int sbase = chunk * 64 + w * 16;
  float* xb = xbuf[w];

  for (int g = 0; g < 4; ++g) {
    const int s0 = sbase + g * 4;
    {
      const int s = s0 + rs;
      const float4 x4 = *(const float4*)(m + ((size_t)s * R_ + r) * C_ + c4);
      const float4 xl = ln_quad(x4, lnw, lnb, c4);
      *(float4*)(xb + rs * 72 + c4) = xl;
    }
    __builtin_amdgcn_wave_barrier();
    // gate GEMM: lane l = output col, 4 rows
    float a0 = 0.f, a1 = 0.f, a2 = 0.f, a3 = 0.f;
#pragma unroll
    for (int c = 0; c < 64; c += 4) {
      const float4 x0 = *(const float4*)(xb + 0 * 72 + c);
      const float4 x1 = *(const float4*)(xb + 1 * 72 + c);
      const float4 x2 = *(const float4*)(xb + 2 * 72 + c);
      const float4 x3 = *(const float4*)(xb + 3 * 72 + c);
      const float w0 = Wg_s[(c + 0) * 64 + l];
      const float w1 = Wg_s[(c + 1) * 64 + l];
      const float w2 = Wg_s[(c + 2) * 64 + l];
      const float w3 = Wg_s[(c + 3) * 64 + l];
      a0 = fmaf(x0.x, w0, fmaf(x0.y, w1, fmaf(x0.z, w2, fmaf(x0.w, w3, a0))));
      a1 = fmaf(x1.x, w0, fmaf(x1.y, w1, fmaf(x1.z, w2, fmaf(x1.w, w3, a1))));
      a2 = fmaf(x2.x, w0, fmaf(x2.y, w1, fmaf(x2.z, w2, fmaf(x2.w, w3, a2))));
      a3 = fmaf(x3.x, w0, fmaf(x3.y, w1, fmaf(x3.z, w2, fmaf(x3.w, w3, a3))));
    }
    const float ov = o_s[l], bgl = bg_s[l];
    const float g0 = ov / (1.f + __expf(-(a0 + bgl)));
    const float g1 = ov / (1.f + __expf(-(a1 + bgl)));
    const float g2 = ov / (1.f + __expf(-(a2 + bgl)));
    const float g3 = ov / (1.f + __expf(-(a3 + bgl)));
    __builtin_amdgcn_wave_barrier();
    xb[0 * 72 + l] = g0;
    xb[1 * 72 + l] = g1;
    xb[2 * 72 + l] = g2;
    xb[3 * 72 + l] = g3;
    __builtin_amdgcn_wave_barrier();
    // output GEMM: out[c=l] = sum_hc og[hc] * Wo[hc][l]
    float b0 = 0.f, b1 = 0.f, b2 = 0.f, b3 = 0.f;
#pragma unroll
    for (int c = 0; c < 64; c += 4) {
      const float4 x0 = *(const float4*)(xb + 0 * 72 + c);
      const float4 x1 = *(const float4*)(xb + 1 * 72 + c);
      const float4 x2 = *(const float4*)(xb + 2 * 72 + c);
      const float4 x3 = *(const float4*)(xb + 3 * 72 + c);
      const float w0 = Wo_s[(c + 0) * 64 + l];
      const float w1 = Wo_s[(c + 1) * 64 + l];
      const float w2 = Wo_s[(c + 2) * 64 + l];
      const float w3 = Wo_s[(c + 3) * 64 + l];
      b0 = fmaf(x0.x, w0, fmaf(x0.y, w1, fmaf(x0.z, w2, fmaf(x0.w, w3, b0))));
      b1 = fmaf(x1.x, w0, fmaf(x1.y, w1, fmaf(x1.z, w2, fmaf(x1.w, w3, b1))));
      b2 = fmaf(x2.x, w0, fmaf(x2.y, w1, fmaf(x2.z, w2, fmaf(x2.w, w3, b2))));
      b3 = fmaf(x3.x, w0, fmaf(x3.y, w1, fmaf(x3.z, w2, fmaf(x3.w, w3, b3))));
    }
    const float bol = bo_s[l];
    out[((size_t)(s0 + 0) * R_ + r) * C_ + l] = b0 + bol;
    out[((size_t)(s0 + 1) * R_ + r) * C_ + l] = b1 + bol;
    out[((size_t)(s0 + 2) * R_ + r) * C_ + l] = b2 + bol;
    out[((size_t)(s0 + 3) * R_ + r) * C_ + l] = b3 + bol;
    __builtin_amdgcn_wave_barrier();
  }
}

extern "C" void kernel_launch(void* const* d_in, const int* in_sizes, int n_in,
                              void* d_out, int out_size, void* d_ws, size_t ws_size,
                              hipStream_t stream) {
  (void)in_sizes; (void)n_in; (void)out_size; (void)ws_size;
  const float* m   = (const float*)d_in[0];
  const float* lnw = (const float*)d_in[1];
  const float* lnb = (const float*)d_in[2];
  const float* Wq  = (const float*)d_in[3];
  const float* Wk  = (const float*)d_in[4];
  const float* Wv  = (const float*)d_in[5];
  const float* Wg  = (const float*)d_in[6];
  const float* bg  = (const float*)d_in[7];
  const float* Wo  = (const float*)d_in[8];
  const float* bo  = (const float*)d_in[9];
  float* out = (float*)d_out;

  float* ws    = (float*)d_ws;
  float* kv    = ws;                                  // R*S*16 floats
  float* qpart = kv + (size_t)R_ * S_ * 16;           // 16*R*64 floats
  float* o_ws  = qpart + (size_t)16 * R_ * 64;        // R*64 floats

  k_lnkv<<<dim3(16, R_), 256, 0, stream>>>(m, lnw, lnb, Wk, Wv, kv, qpart);
  k_attn<<<dim3(R_), 256, 0, stream>>>(qpart, Wq, kv, o_ws);
  k_out<<<dim3(32, R_), 256, 0, stream>>>(m, lnw, lnb, Wg, bg, Wo, bo, o_ws, out);
}

// Round 2
// 472.046 us; speedup vs baseline: 1.5512x; 1.5512x over previous
//
#include <hip/hip_runtime.h>
#include <math.h>

#define S_ 2048
#define R_ 384

typedef __attribute__((ext_vector_type(8))) short bf16x8;
typedef __attribute__((ext_vector_type(4))) float f32x4;

static __device__ __forceinline__ f32x4 mfma16(bf16x8 a, bf16x8 b, f32x4 c) {
  return __builtin_amdgcn_mfma_f32_16x16x32_bf16(a, b, c, 0, 0, 0);
}

// fp32 -> bf16 round-to-nearest-even
static __device__ __forceinline__ unsigned short f2bf(float f) {
  unsigned u = __float_as_uint(f);
  u += 0x7fffu + ((u >> 16) & 1u);
  return (unsigned short)(u >> 16);
}
static __device__ __forceinline__ float bflo(unsigned u) {
  return __uint_as_float(u << 16);
}
static __device__ __forceinline__ float bfhi(unsigned u) {
  return __uint_as_float(u & 0xffff0000u);
}

// LayerNorm of one 64-float row spread across a 16-lane group (lane holds 4
// consecutive c at c4). Wave-synchronous shfl reduction within the group.
__device__ __forceinline__ float4 ln_quad(const float4 x4, const float* lnw,
                                          const float* lnb, int c4) {
  float s1 = x4.x + x4.y + x4.z + x4.w;
  float s2 = fmaf(x4.x, x4.x, fmaf(x4.y, x4.y, fmaf(x4.z, x4.z, x4.w * x4.w)));
#pragma unroll
  for (int msk = 1; msk <= 8; msk <<= 1) {
    s1 += __shfl_xor(s1, msk);
    s2 += __shfl_xor(s2, msk);
  }
  float mu  = s1 * (1.f / 64.f);
  float var = fmaf(-mu, mu, s2 * (1.f / 64.f));
  float inv = rsqrtf(var + 1e-5f);
  float nb  = -mu * inv;
  float4 xl;
  xl.x = fmaf(fmaf(x4.x, inv, nb), lnw[c4 + 0], lnb[c4 + 0]);
  xl.y = fmaf(fmaf(x4.y, inv, nb), lnw[c4 + 1], lnb[c4 + 1]);
  xl.z = fmaf(fmaf(x4.z, inv, nb), lnw[c4 + 2], lnb[c4 + 2]);
  xl.w = fmaf(fmaf(x4.w, inv, nb), lnw[c4 + 3], lnb[c4 + 3]);
  return xl;
}

// ---------------- Kernel 1: LN + K/V (MFMA) + partial Q-sums ----------------
// grid (8, R), block 256 (4 waves). Block covers 256 s-rows of column r.
// kv stored bf16 [r][s][16] (k: 0-7, v: 8-15).
__global__ __launch_bounds__(256) void k_lnkv(
    const float* __restrict__ m, const float* __restrict__ lnw_g,
    const float* __restrict__ lnb_g, const float* __restrict__ Wk,
    const float* __restrict__ Wv, unsigned short* __restrict__ kv,
    float* __restrict__ qpart) {
  __shared__ unsigned short xt[4][16 * 72];  // per-wave bf16 x-tile, pad 72
  __shared__ float lnw[64], lnb[64];
  __shared__ float qred[4][64];

  const int t = threadIdx.x;
  const int w = t >> 6, l = t & 63;
  const int lane_n = l & 15, quad = l >> 4;
  const int r = blockIdx.y, chunk = blockIdx.x;

  if (t < 64) { lnw[t] = lnw_g[t]; lnb[t] = lnb_g[t]; }

  // B-frags for [Wk|Wv] (N=16, K=64 -> 2 frags), resident in registers.
  bf16x8 bkv[2];
#pragma unroll
  for (int kk = 0; kk < 2; ++kk) {
#pragma unroll
    for (int j = 0; j < 8; ++j) {
      const int k = kk * 32 + quad * 8 + j;
      const float wv_ = (lane_n < 8) ? Wk[k * 8 + lane_n] : Wv[k * 8 + lane_n - 8];
      ((unsigned short*)&bkv[kk])[j] = f2bf(wv_);
    }
  }
  __syncthreads();

  unsigned short* xw = xt[w];
  const int c4 = lane_n * 4;
  float4 qacc = make_float4(0.f, 0.f, 0.f, 0.f);

  for (int it = 0; it < 4; ++it) {
    const int s0 = chunk * 256 + it * 64 + w * 16;
#pragma unroll
    for (int p = 0; p < 4; ++p) {
      const int row = p * 4 + quad;
      const float4 x4 = *(const float4*)(m + ((size_t)(s0 + row) * R_ + r) * 64 + c4);
      const float4 xl = ln_quad(x4, lnw, lnb, c4);
      qacc.x += xl.x; qacc.y += xl.y; qacc.z += xl.z; qacc.w += xl.w;
      ushort4 pk;
      pk.x = f2bf(xl.x); pk.y = f2bf(xl.y); pk.z = f2bf(xl.z); pk.w = f2bf(xl.w);
      *(ushort4*)(xw + row * 72 + c4) = pk;
    }
    __builtin_amdgcn_wave_barrier();
    const bf16x8 a0 = *(const bf16x8*)(xw + lane_n * 72 + quad * 8);
    const bf16x8 a1 = *(const bf16x8*)(xw + lane_n * 72 + 32 + quad * 8);
    f32x4 acc = {0.f, 0.f, 0.f, 0.f};
    acc = mfma16(a0, bkv[0], acc);
    acc = mfma16(a1, bkv[1], acc);
#pragma unroll
    for (int rg = 0; rg < 4; ++rg)
      kv[((size_t)r * S_ + s0 + quad * 4 + rg) * 16 + lane_n] = f2bf(acc[rg]);
    __builtin_amdgcn_wave_barrier();
  }

  // reduce q partials across row slots (lane bits 4,5)
#pragma unroll
  for (int msk = 16; msk <= 32; msk <<= 1) {
    qacc.x += __shfl_xor(qacc.x, msk);
    qacc.y += __shfl_xor(qacc.y, msk);
    qacc.z += __shfl_xor(qacc.z, msk);
    qacc.w += __shfl_xor(qacc.w, msk);
  }
  if (l < 16) *(float4*)(&qred[w][c4]) = qacc;
  __syncthreads();
  if (t < 64)
    qpart[((size_t)chunk * R_ + r) * 64 + t] =
        qred[0][t] + qred[1][t] + qred[2][t] + qred[3][t];
}

// ---------------- Kernel 2: pooled q + attention ----------------
// grid (R), block 256. Two-pass softmax with logit recomputation.
__global__ __launch_bounds__(256) void k_attn(
    const float* __restrict__ qpart, const float* __restrict__ Wq,
    const unsigned short* __restrict__ kv, float* __restrict__ o_ws) {
  __shared__ float qs[64];
  __shared__ float q[64];
  __shared__ float mred[8 * 32];
  __shared__ float lred[8 * 32];
  __shared__ float opart[32 * 64];

  const int t = threadIdx.x, r = blockIdx.x;

  if (t < 64) {
    float s = 0.f;
#pragma unroll
    for (int ch = 0; ch < 8; ++ch) s += qpart[((size_t)ch * R_ + r) * 64 + t];
    qs[t] = s * (1.f / 2048.f);   // /(S+1e-10) rounds to /2048 in fp32
  }
  __syncthreads();
  if (t < 64) {
    float acc = 0.f;
    for (int c = 0; c < 64; ++c) acc = fmaf(qs[c], Wq[c * 64 + t], acc);
    q[t] = acc * 0.35355339059327373f;   // Ch^-0.5
  }
  __syncthreads();

  const int h = t & 7, part = t >> 3;
  float qh[8];
#pragma unroll
  for (int j = 0; j < 8; ++j) qh[j] = q[h * 8 + j];

  // pass 1: per-head max of logits over this thread's s range
  float mx = -1e30f;
  for (int s = part * 64; s < part * 64 + 64; ++s) {
    const unsigned short* kp = kv + ((size_t)r * S_ + s) * 16;
    const uint4 kr = *(const uint4*)kp;
    float d;
    d = qh[0] * bflo(kr.x) + qh[1] * bfhi(kr.x);
    d = fmaf(qh[2], bflo(kr.y), fmaf(qh[3], bfhi(kr.y), d));
    d = fmaf(qh[4], bflo(kr.z), fmaf(qh[5], bfhi(kr.z), d));
    d = fmaf(qh[6], bflo(kr.w), fmaf(qh[7], bfhi(kr.w), d));
    mx = fmaxf(mx, d);
  }
  mred[h * 32 + part] = mx;
  __syncthreads();
  float mh = -1e30f;
  for (int p = 0; p < 32; ++p) mh = fmaxf(mh, mred[h * 32 + p]);

  // pass 2: exp-sum + unnormalized o accumulation
  float l_acc = 0.f;
  float av[8];
#pragma unroll
  for (int j = 0; j < 8; ++j) av[j] = 0.f;
  for (int s = part * 64; s < part * 64 + 64; ++s) {
    const unsigned short* kp = kv + ((size_t)r * S_ + s) * 16;
    const uint4 kr = *(const uint4*)kp;
    const uint4 vr = *(const uint4*)(kp + 8);
    float d;
    d = qh[0] * bflo(kr.x) + qh[1] * bfhi(kr.x);
    d = fmaf(qh[2], bflo(kr.y), fmaf(qh[3], bfhi(kr.y), d));
    d = fmaf(qh[4], bflo(kr.z), fmaf(qh[5], bfhi(kr.z), d));
    d = fmaf(qh[6], bflo(kr.w), fmaf(qh[7], bfhi(kr.w), d));
    const float e = __expf(d - mh);
    l_acc += e;
    av[0] = fmaf(e, bflo(vr.x), av[0]); av[1] = fmaf(e, bfhi(vr.x), av[1]);
    av[2] = fmaf(e, bflo(vr.y), av[2]); av[3] = fmaf(e, bfhi(vr.y), av[3]);
    av[4] = fmaf(e, bflo(vr.z), av[4]); av[5] = fmaf(e, bfhi(vr.z), av[5]);
    av[6] = fmaf(e, bflo(vr.w), av[6]); av[7] = fmaf(e, bfhi(vr.w), av[7]);
  }
  lred[h * 32 + part] = l_acc;
#pragma unroll
  for (int j = 0; j < 8; ++j) opart[part * 64 + h * 8 + j] = av[j];
  __syncthreads();

  if (t < 64) {
    const int hh = t >> 3;
    float denom = 0.f;
    for (int p = 0; p < 32; ++p) denom += lred[hh * 32 + p];
    float acc = 0.f;
    for (int p = 0; p < 32; ++p) acc += opart[p * 64 + t];
    o_ws[(size_t)r * 64 + t] = acc / denom;
  }
}

// ---------------- Kernel 3: LN + gate GEMM + output GEMM (MFMA) ----------------
// grid (8, R), block 256 (4 waves). o folded into Wo: out = g @ (o .* Wo) + bo.
__global__ __launch_bounds__(256) void k_out(
    const float* __restrict__ m, const float* __restrict__ lnw_g,
    const float* __restrict__ lnb_g, const float* __restrict__ Wg,
    const float* __restrict__ bg, const float* __restrict__ Wo,
    const float* __restrict__ bo, const float* __restrict__ o_ws,
    float* __restrict__ out) {
  __shared__ unsigned short xt[4][16 * 72];
  __shared__ float lnw[64], lnb[64];

  const int t = threadIdx.x;
  const int w = t >> 6, l = t & 63;
  const int lane_n = l & 15, quad = l >> 4;
  const int r = blockIdx.y, chunk = blockIdx.x;

  if (t < 64) { lnw[t] = lnw_g[t]; lnb[t] = lnb_g[t]; }

  // Weight B-frags in registers: Wg and o.*Wo, 4 N-tiles x 2 K-steps each.
  bf16x8 Bg[4][2], Bo[4][2];
  float bgv[4], bov[4];
#pragma unroll
  for (int n = 0; n < 4; ++n) {
    bgv[n] = bg[n * 16 + lane_n];
    bov[n] = bo[n * 16 + lane_n];
#pragma unroll
    for (int kk = 0; kk < 2; ++kk) {
#pragma unroll
      for (int j = 0; j < 8; ++j) {
        const int k = kk * 32 + quad * 8 + j;
        ((unsigned short*)&Bg[n][kk])[j] = f2bf(Wg[k * 64 + n * 16 + lane_n]);
        ((unsigned short*)&Bo[n][kk])[j] =
            f2bf(o_ws[(size_t)r * 64 + k] * Wo[k * 64 + n * 16 + lane_n]);
      }
    }
  }
  __syncthreads();

  unsigned short* xw = xt[w];
  const int c4 = lane_n * 4;

  for (int it = 0; it < 4; ++it) {
    const int s0 = chunk * 256 + it * 64 + w * 16;
#pragma unroll
    for (int p = 0; p < 4; ++p) {
      const int row = p * 4 + quad;
      const float4 x4 = *(const float4*)(m + ((size_t)(s0 + row) * R_ + r) * 64 + c4);
      const float4 xl = ln_quad(x4, lnw, lnb, c4);
      ushort4 pk;
      pk.x = f2bf(xl.x); pk.y = f2bf(xl.y); pk.z = f2bf(xl.z); pk.w = f2bf(xl.w);
      *(ushort4*)(xw + row * 72 + c4) = pk;
    }
    __builtin_amdgcn_wave_barrier();
    const bf16x8 a0 = *(const bf16x8*)(xw + lane_n * 72 + quad * 8);
    const bf16x8 a1 = *(const bf16x8*)(xw + lane_n * 72 + 32 + quad * 8);
    f32x4 gacc[4];
#pragma unroll
    for (int n = 0; n < 4; ++n) {
      f32x4 z = {0.f, 0.f, 0.f, 0.f};
      z = mfma16(a0, Bg[n][0], z);
      gacc[n] = mfma16(a1, Bg[n][1], z);
    }
    __builtin_amdgcn_wave_barrier();
    // sigmoid gate -> bf16 -> same LDS tile in row-major [s][hc]
#pragma unroll
    for (int n = 0; n < 4; ++n) {
#pragma unroll
      for (int reg = 0; reg < 4; ++reg) {
        const float gv = 1.f / (1.f + __expf(-(gacc[n][reg] + bgv[n])));
        xw[(quad * 4 + reg) * 72 + n * 16 + lane_n] = f2bf(gv);
      }
    }
    __builtin_amdgcn_wave_barrier();
    const bf16x8 g0 = *(const bf16x8*)(xw + lane_n * 72 + quad * 8);
    const bf16x8 g1 = *(const bf16x8*)(xw + lane_n * 72 + 32 + quad * 8);
    f32x4 oacc[4];
#pragma unroll
    for (int n = 0; n < 4; ++n) {
      f32x4 z = {0.f, 0.f, 0.f, 0.f};
      z = mfma16(g0, Bo[n][0], z);
      oacc[n] = mfma16(g1, Bo[n][1], z);
    }
#pragma unroll
    for (int n = 0; n < 4; ++n) {
#pragma unroll
      for (int reg = 0; reg < 4; ++reg) {
        out[((size_t)(s0 + quad * 4 + reg) * R_ + r) * 64 + n * 16 + lane_n] =
            oacc[n][reg] + bov[n];
      }
    }
    __builtin_amdgcn_wave_barrier();
  }
}

extern "C" void kernel_launch(void* const* d_in, const int* in_sizes, int n_in,
                              void* d_out, int out_size, void* d_ws, size_t ws_size,
                              hipStream_t stream) {
  (void)in_sizes; (void)n_in; (void)out_size; (void)ws_size;
  const float* m   = (const float*)d_in[0];
  const float* lnw = (const float*)d_in[1];
  const float* lnb = (const float*)d_in[2];
  const float* Wq  = (const float*)d_in[3];
  const float* Wk  = (const float*)d_in[4];
  const float* Wv  = (const float*)d_in[5];
  const float* Wg  = (const float*)d_in[6];
  const float* bg  = (const float*)d_in[7];
  const float* Wo  = (const float*)d_in[8];
  const float* bo  = (const float*)d_in[9];
  float* out = (float*)d_out;

  // ws layout: kv bf16 [R*S*16] | qpart f32 [8*R*64] | o f32 [R*64]  (~26 MB)
  unsigned short* kv = (unsigned short*)d_ws;
  float* qpart = (float*)((char*)d_ws + (size_t)R_ * S_ * 16 * 2);
  float* o_ws  = qpart + (size_t)8 * R_ * 64;

  k_lnkv<<<dim3(8, R_), 256, 0, stream>>>(m, lnw, lnb, Wk, Wv, kv, qpart);
  k_attn<<<dim3(R_), 256, 0, stream>>>(qpart, Wq, kv, o_ws);
  k_out<<<dim3(8, R_), 256, 0, stream>>>(m, lnw, lnb, Wg, bg, Wo, bo, o_ws, out);
}